// Round 1
// baseline (457.364 us; speedup 1.0000x reference)
//
#include <hip/hip_runtime.h>
#include <cstdint>

#define NEXP 8
#define TOPK 2
#define NTOK 4096
#define NSLOT (NTOK * TOPK)   // 8192
#define CAP 1280              // expert capacity (1.25 * 2*4096/8, mult of 8)
#define DM 2048               // d_model == hidden
#define EC (NEXP * CAP)       // 10240 rows in binned space

typedef __bf16 bf16x8 __attribute__((ext_vector_type(8)));
typedef __bf16 bf16x2 __attribute__((ext_vector_type(2)));
typedef float  f32x4  __attribute__((ext_vector_type(4)));

typedef const void __attribute__((address_space(1))) gvoid;
typedef void __attribute__((address_space(3))) lvoid;

// global->LDS direct copy, 16B per lane. LDS dest is wave-uniform base,
// lane i lands at base + i*16. AS casts via uintptr_t (generic->AS3 is a
// low-32-bit truncation on amdgcn; shared aperture is 4GB-aligned).
__device__ __forceinline__ void gld16(const void* g, void* l) {
  __builtin_amdgcn_global_load_lds((gvoid*)(uintptr_t)g, (lvoid*)(uintptr_t)l,
                                   16, 0, 0);
}

// ---------------------------------------------------------------- routing
// Reproduces: stable sort by expert id; pos = rank within expert; drop pos>=CAP.
__global__ void route_k(const int* __restrict__ eidx, int* __restrict__ row_token,
                        int* __restrict__ slot_dest, int* __restrict__ mcount,
                        float* __restrict__ out) {
  __shared__ int lh[256][NEXP];
  int tid = threadIdx.x;
  for (int i = tid; i < EC; i += 256) row_token[i] = -1;
#pragma unroll
  for (int e = 0; e < NEXP; ++e) lh[tid][e] = 0;
  __syncthreads();
  int base = tid * 32;                       // 256 threads * 32 slots = 8192
  for (int j = 0; j < 32; ++j) {
    int e = eidx[base + j];
    lh[tid][e]++;
  }
  __syncthreads();
  if (tid < NEXP) {                          // exclusive prefix per expert
    int run = 0;
    for (int i = 0; i < 256; ++i) { int t = lh[i][tid]; lh[i][tid] = run; run += t; }
    mcount[tid] = run < CAP ? run : CAP;
    out[(size_t)NTOK * DM + tid] = (float)run;   // counts output (exact ints)
  }
  __syncthreads();
  for (int j = 0; j < 32; ++j) {             // in-order walk => stable rank
    int t = base + j;
    int e = eidx[t];
    int r = lh[tid][e]++;
    if (r < CAP) { int dst = e * CAP + r; slot_dest[t] = dst; row_token[dst] = t >> 1; }
    else slot_dest[t] = -1;
  }
}

// ------------------------------------------------------- gather + fp32->bf16
__global__ void gather_k(const float* __restrict__ x, const int* __restrict__ row_token,
                         __bf16* __restrict__ xg) {
  int r = blockIdx.x;
  int c = threadIdx.x * 8;
  int tok = row_token[r];
  bf16x8 o;
  if (tok >= 0) {
    const float* src = x + (size_t)tok * DM + c;
    float4 a = *(const float4*)src;
    float4 b = *(const float4*)(src + 4);
    o[0] = (__bf16)a.x; o[1] = (__bf16)a.y; o[2] = (__bf16)a.z; o[3] = (__bf16)a.w;
    o[4] = (__bf16)b.x; o[5] = (__bf16)b.y; o[6] = (__bf16)b.z; o[7] = (__bf16)b.w;
  } else {
#pragma unroll
    for (int j = 0; j < 8; ++j) o[j] = (__bf16)0.f;
  }
  *(bf16x8*)(xg + (size_t)r * DM + c) = o;
}

// --------------------------------------- fp32 [E][K][N] -> bf16 [E][N][K]
__global__ void transT_k(const float* __restrict__ w, __bf16* __restrict__ wT) {
  __shared__ __bf16 t[64][65];               // +1 pad: conflict-free transpose
  int e = blockIdx.z;
  int n0 = blockIdx.x * 64, k0 = blockIdx.y * 64;
  const float* src = w + ((size_t)e << 22) + (size_t)k0 * DM + n0;
  __bf16* dst = wT + ((size_t)e << 22) + (size_t)n0 * DM + k0;
  int c = threadIdx.x & 63, r4 = threadIdx.x >> 6;
#pragma unroll
  for (int p = 0; p < 16; ++p) {
    int r = p * 4 + r4;
    t[r][c] = (__bf16)src[(size_t)r * DM + c];
  }
  __syncthreads();
  int j = threadIdx.x & 31, rr8 = threadIdx.x >> 5;
#pragma unroll
  for (int q = 0; q < 8; ++q) {
    int rr = q * 8 + rr8;
    bf16x2 v;
    v[0] = t[2 * j][rr];
    v[1] = t[2 * j + 1][rr];
    *(bf16x2*)(dst + (size_t)rr * DM + 2 * j) = v;
  }
}

// ------------------------------------------------------------------- GEMM
// C[rows,N] = A[rows,K] * BT[N,K]^T  per expert, bf16 in, bf16 out, f32 acc.
// 128x128 tile, BK=64, 4 waves (2x2), 16x16x32 MFMA.
// LDS layout XOR-swizzled: logical (row,k) at byte row*128 + ((k*2)^((row&7)<<4)).
// Staged via global_load_lds with inverse-swizzled per-lane GLOBAL source
// (linear LDS dest), read back with the same swizzle (rule #21).
__global__ __launch_bounds__(256, 2)
void gemm_k(const __bf16* __restrict__ A0, const __bf16* __restrict__ BT,
            __bf16* __restrict__ C, const int* __restrict__ mcount) {
  int e = blockIdx.z, mt = blockIdx.y, nt = blockIdx.x;
  int mc = mcount[e];
  if (mt * 128 >= mc) return;                // skip empty capacity tiles

  __shared__ __align__(16) char smem[128 * 64 * 2 * 2];  // A tile + B tile
  char* lA = smem;
  char* lB = smem + 128 * 64 * 2;

  int row0 = e * CAP + mt * 128;
  const char* gA = (const char*)(A0 + (size_t)row0 * DM);
  const char* gB = (const char*)(BT + ((size_t)e * DM + (size_t)nt * 128) * DM);

  int tid = threadIdx.x, w = tid >> 6, l = tid & 63;
  int wr = w >> 1, wc = w & 1;
  int sr = l >> 3;                           // staging: row within 8-row group
  int sc = l & 7;                            // staging: stored 16B chunk

  f32x4 acc[4][4];
#pragma unroll
  for (int m = 0; m < 4; ++m)
#pragma unroll
    for (int n = 0; n < 4; ++n)
#pragma unroll
      for (int j = 0; j < 4; ++j) acc[m][n][j] = 0.f;

  int lr = l & 15, kg = l >> 4;

  for (int ks = 0; ks < 32; ++ks) {          // K = 2048 = 32 * 64
    // ---- stage A and B tiles (128 rows x 64 bf16 = 128B/row each)
#pragma unroll
    for (int i = 0; i < 4; ++i) {
      int g = i * 4 + w;                     // 16 8-row groups, uniform per wave
      int r = g * 8 + sr;
      int cl = sc ^ (r & 7);                 // inverse-swizzled source chunk
      size_t goff = (size_t)r * (DM * 2) + (size_t)ks * 128 + (size_t)cl * 16;
      gld16(gA + goff, lA + g * 1024);
      gld16(gB + goff, lB + g * 1024);
    }
    __syncthreads();
    // ---- compute 2 x K=32 MFMA slabs
#pragma unroll
    for (int kk = 0; kk < 2; ++kk) {
      int chunk = kk * 4 + kg;               // logical 8-elem chunk index
      bf16x8 af[4], bf[4];
#pragma unroll
      for (int m = 0; m < 4; ++m) {
        int r = wr * 64 + m * 16 + lr;
        af[m] = *(const bf16x8*)(lA + r * 128 + ((chunk ^ (r & 7)) * 16));
      }
#pragma unroll
      for (int n = 0; n < 4; ++n) {
        int r = wc * 64 + n * 16 + lr;
        bf[n] = *(const bf16x8*)(lB + r * 128 + ((chunk ^ (r & 7)) * 16));
      }
#pragma unroll
      for (int m = 0; m < 4; ++m)
#pragma unroll
        for (int n = 0; n < 4; ++n)
          acc[m][n] = __builtin_amdgcn_mfma_f32_16x16x32_bf16(af[m], bf[n],
                                                              acc[m][n], 0, 0, 0);
    }
    __syncthreads();
  }

  // ---- epilogue: C/D layout col=lane&15, row=(lane>>4)*4+j  [m89-verified]
  int rg = l >> 4;
#pragma unroll
  for (int m = 0; m < 4; ++m)
#pragma unroll
    for (int n = 0; n < 4; ++n)
#pragma unroll
      for (int j = 0; j < 4; ++j) {
        int rr = row0 + wr * 64 + m * 16 + rg * 4 + j;
        int cc = nt * 128 + wc * 64 + n * 16 + lr;
        C[(size_t)rr * DM + cc] = (__bf16)acc[m][n][j];
      }
}

// ------------------------------------------------ h = silu(u) * v (in-place u)
__global__ void swiglu_k(__bf16* __restrict__ u, const __bf16* __restrict__ v) {
  size_t i = ((size_t)blockIdx.x * 256 + threadIdx.x) * 8;
  bf16x8 a = *(bf16x8*)(u + i);
  bf16x8 b = *(const bf16x8*)(v + i);
  bf16x8 o;
#pragma unroll
  for (int j = 0; j < 8; ++j) {
    float xx = (float)a[j];
    float s = xx / (1.f + __expf(-xx));
    o[j] = (__bf16)(s * (float)b[j]);
  }
  *(bf16x8*)(u + i) = o;
}

// --------------------------------------------- combine: y[tok] = sum w * ye
__global__ void combine_k(const __bf16* __restrict__ ye, const int* __restrict__ slot_dest,
                          const float* __restrict__ ew, float* __restrict__ out) {
  int tok = blockIdx.x;
  int c = threadIdx.x * 8;
  int d0 = slot_dest[2 * tok], d1 = slot_dest[2 * tok + 1];
  float w0 = ew[2 * tok], w1 = ew[2 * tok + 1];
  float r[8];
#pragma unroll
  for (int j = 0; j < 8; ++j) r[j] = 0.f;
  if (d0 >= 0) {
    bf16x8 y0 = *(const bf16x8*)(ye + (size_t)d0 * DM + c);
#pragma unroll
    for (int j = 0; j < 8; ++j) r[j] += w0 * (float)y0[j];
  }
  if (d1 >= 0) {
    bf16x8 y1 = *(const bf16x8*)(ye + (size_t)d1 * DM + c);
#pragma unroll
    for (int j = 0; j < 8; ++j) r[j] += w1 * (float)y1[j];
  }
  float* dst = out + (size_t)tok * DM + c;
  float4 o0; o0.x = r[0]; o0.y = r[1]; o0.z = r[2]; o0.w = r[3];
  float4 o1; o1.x = r[4]; o1.y = r[5]; o1.z = r[6]; o1.w = r[7];
  *(float4*)dst = o0;
  *(float4*)(dst + 4) = o1;
}

extern "C" void kernel_launch(void* const* d_in, const int* in_sizes, int n_in,
                              void* d_out, int out_size, void* d_ws, size_t ws_size,
                              hipStream_t stream) {
  const float* x  = (const float*)d_in[0];
  const float* ew = (const float*)d_in[1];
  const int*   ei = (const int*)d_in[2];
  const float* w1 = (const float*)d_in[3];
  const float* w2 = (const float*)d_in[4];
  const float* w3 = (const float*)d_in[5];
  float* out = (float*)d_out;
  char* ws = (char*)d_ws;

  // ws layout (~193 MB): xg | u(->h) | v(->ye) | wT (reused 3x) | routing ints
  const size_t SZ_MAT = (size_t)EC * DM * 2;            // 41,943,040 B
  __bf16* xg = (__bf16*)ws;
  __bf16* uB = (__bf16*)(ws + SZ_MAT);
  __bf16* vB = (__bf16*)(ws + 2 * SZ_MAT);
  __bf16* wT = (__bf16*)(ws + 3 * SZ_MAT);              // [8][2048][2048] bf16
  char* ints = ws + 3 * SZ_MAT + (size_t)NEXP * DM * DM * 2;
  int* row_token = (int*)ints;                          // [EC]
  int* slot_dest = row_token + EC;                      // [NSLOT]
  int* mcount    = slot_dest + NSLOT;                   // [NEXP]

  dim3 tgrid(32, 32, NEXP);
  dim3 ggrid(16, 10, NEXP);                             // nt, mt(cap/128), e

  route_k<<<1, 256, 0, stream>>>(ei, row_token, slot_dest, mcount, out);
  gather_k<<<EC, 256, 0, stream>>>(x, row_token, xg);

  transT_k<<<tgrid, 256, 0, stream>>>(w1, wT);
  gemm_k<<<ggrid, 256, 0, stream>>>(xg, wT, uB, mcount);   // u = xg @ w1

  transT_k<<<tgrid, 256, 0, stream>>>(w3, wT);
  gemm_k<<<ggrid, 256, 0, stream>>>(xg, wT, vB, mcount);   // v = xg @ w3

  swiglu_k<<<EC, 256, 0, stream>>>(uB, vB);                // u <- silu(u)*v

  transT_k<<<tgrid, 256, 0, stream>>>(w2, wT);
  gemm_k<<<ggrid, 256, 0, stream>>>(uB, wT, vB, mcount);   // ye = h @ w2

  combine_k<<<NTOK, 256, 0, stream>>>(vB, slot_dest, ew, out);
}